// Round 1
// baseline (670.353 us; speedup 1.0000x reference)
//
#include <hip/hip_runtime.h>
#include <cmath>

// GHM-C two-stage loss, single data pass.
// loss = (1/N) * sum_b beta_b * sum_ce[b],  beta_b = 1/clip(cnt_b*nonempty, 1e-4)
// One wave (64 lanes) per row; lane == class index (C == 64).
// Bin 9 (~99% of samples for this input distribution) accumulates in registers,
// rare bins use global fp64 atomics directly.

#define BINS 10

__global__ __launch_bounds__(256) void ghmc_main_kernel(
    const float* __restrict__ x,
    const int* __restrict__ target,
    const float* __restrict__ weight,
    const int* __restrict__ stage_p,
    double* __restrict__ g_ce,        // [BINS] fp64 sum of ce per bin
    unsigned int* __restrict__ g_cnt, // [BINS] counts
    int N)
{
    const int lane = threadIdx.x & 63;
    const int wave_in_block = threadIdx.x >> 6;
    const unsigned int wave_id = blockIdx.x * 4u + wave_in_block;
    const unsigned int nwaves = gridDim.x * 4u;
    const int stage = *stage_p;

    unsigned int cnt9 = 0;
    double ce9 = 0.0;

    for (unsigned int row = wave_id; row < (unsigned int)N; row += nwaves) {
        float v = x[((size_t)row << 6) + (unsigned)lane];

        // wave max (butterfly: identical result all lanes)
        float m = v;
        #pragma unroll
        for (int off = 32; off > 0; off >>= 1)
            m = fmaxf(m, __shfl_xor(m, off, 64));

        float e = expf(v - m);
        float s = e;
        #pragma unroll
        for (int off = 32; off > 0; off >>= 1)
            s += __shfl_xor(s, off, 64);

        int t = target[row];  // same address all lanes -> broadcast
        if (lane == t) {
            // fp32 sequence mirrors the reference exactly
            float log_pt = (v - m) - logf(s);
            float w = (stage == 1) ? 1.0f : weight[t];
            float ce = -(w * log_pt);
            float pt = expf(log_pt);
            float g = fabsf(pt - 1.0f);
            int b = (int)floorf(g * 9.9999f);   // BINS - EPS_BIN in fp32
            b = b < 0 ? 0 : (b > 9 ? 9 : b);
            if (b == 9) {
                cnt9++;
                ce9 += (double)ce;
            } else {
                atomicAdd(&g_cnt[b], 1u);
                atomicAdd(&g_ce[b], (double)ce);
            }
        }
    }

    // wave-reduce the dominant bin, one atomic per wave
    #pragma unroll
    for (int off = 32; off > 0; off >>= 1) {
        cnt9 += __shfl_xor(cnt9, off, 64);
        ce9  += __shfl_xor(ce9, off, 64);
    }
    if (lane == 0 && cnt9 > 0) {
        atomicAdd(&g_cnt[9], cnt9);
        atomicAdd(&g_ce[9], ce9);
    }
}

__global__ void ghmc_final_kernel(const double* __restrict__ g_ce,
                                  const unsigned int* __restrict__ g_cnt,
                                  float* __restrict__ out, int N)
{
    if (threadIdx.x == 0) {
        int nonempty = 0;
        #pragma unroll
        for (int b = 0; b < BINS; b++) nonempty += (g_cnt[b] > 0) ? 1 : 0;
        double total = 0.0;
        #pragma unroll
        for (int b = 0; b < BINS; b++) {
            // mirror reference fp32 semantics for gd (products are exact ints < 2^24 anyway)
            float gd = (float)g_cnt[b] * (float)nonempty;
            gd = fmaxf(gd, 1e-4f);
            total += g_ce[b] / (double)gd;
        }
        out[0] = (float)(total / (double)N);
    }
}

extern "C" void kernel_launch(void* const* d_in, const int* in_sizes, int n_in,
                              void* d_out, int out_size, void* d_ws, size_t ws_size,
                              hipStream_t stream) {
    const float* x       = (const float*)d_in[0];
    const int* target    = (const int*)d_in[1];
    const float* weight  = (const float*)d_in[2];
    const int* stage_p   = (const int*)d_in[3];
    const int N = in_sizes[1];          // rows; C == 64 (in_sizes[2]) assumed

    double* g_ce = (double*)d_ws;
    unsigned int* g_cnt = (unsigned int*)(g_ce + BINS);

    // d_ws is re-poisoned 0xAA before every launch -> zero our accumulators
    hipMemsetAsync(d_ws, 0, BINS * sizeof(double) + BINS * sizeof(unsigned int), stream);

    const int blocks = 2048;            // 8192 waves, grid-stride over rows
    ghmc_main_kernel<<<blocks, 256, 0, stream>>>(x, target, weight, stage_p,
                                                 g_ce, g_cnt, N);
    ghmc_final_kernel<<<1, 64, 0, stream>>>(g_ce, g_cnt, (float*)d_out, N);
}

// Round 2
// 661.312 us; speedup vs baseline: 1.0137x; 1.0137x over previous
//
#include <hip/hip_runtime.h>
#include <cmath>

// GHM-C two-stage loss, single data pass.
// loss = (1/N) * sum_b beta_b * sum_ce[b],  beta_b = 1/clip(cnt_b*nonempty, 1e-4)
//
// R2: 4 rows per wave via float4 loads (16 lanes/row, 4 elems/lane), 16-lane
// butterfly reductions (4 shfl instead of 6), unrolled x2 -> 8 rows in flight
// per wave iteration. Attacks the R1 latency bound (413 us @ 32% VALUBusy,
// 0.37 TB/s: serial 12-shfl chain per row).

#define BINS 10

__global__ __launch_bounds__(256) void ghmc_main_kernel(
    const float* __restrict__ x,
    const int* __restrict__ target,
    const float* __restrict__ weight,
    const int* __restrict__ stage_p,
    double* __restrict__ g_ce,        // [BINS] fp64 sum of ce per bin
    unsigned int* __restrict__ g_cnt, // [BINS] counts
    int N)
{
    const int lane    = threadIdx.x & 63;
    const int grp     = lane >> 4;        // row within 4-row pack
    const int sub     = lane & 15;        // float4 index within row
    const int slot_hi = sub << 2;         // first element index this lane holds

    const unsigned int wave_id = blockIdx.x * 4u + (threadIdx.x >> 6);
    const unsigned int nwaves  = gridDim.x * 4u;
    const int stage = *stage_p;

    const float4* __restrict__ x4 = (const float4*)x;
    const unsigned int G = ((unsigned int)N + 3u) >> 2;   // 4-row packs

    unsigned int cnt9 = 0;
    double ce9 = 0.0;

    for (unsigned int p = wave_id * 2u; p < G; p += nwaves * 2u) {
        #pragma unroll
        for (int u = 0; u < 2; u++) {
            unsigned int pk = p + (unsigned int)u;
            if (pk >= G) break;
            unsigned int row = pk * 4u + (unsigned int)grp;
            if (row >= (unsigned int)N) continue;

            // lane loads its 4 elements of its row: contiguous 1KiB per wave
            float4 v = x4[((size_t)row << 4) + (unsigned)sub];

            // row max: 3 in-lane + 4 shfl over the 16-lane group
            float m = fmaxf(fmaxf(v.x, v.y), fmaxf(v.z, v.w));
            #pragma unroll
            for (int off = 1; off < 16; off <<= 1)
                m = fmaxf(m, __shfl_xor(m, off, 64));

            // sum of exp(v - m)
            float e0 = expf(v.x - m), e1 = expf(v.y - m);
            float e2 = expf(v.z - m), e3 = expf(v.w - m);
            float s = (e0 + e1) + (e2 + e3);
            #pragma unroll
            for (int off = 1; off < 16; off <<= 1)
                s += __shfl_xor(s, off, 64);

            int t = target[row];   // same addr across the 16-lane group
            if (sub == (t >> 2)) {
                int sl = t & 3;
                float vt = (sl == 0) ? v.x : (sl == 1) ? v.y : (sl == 2) ? v.z : v.w;
                // fp32 sequence mirrors the reference
                float log_pt = (vt - m) - logf(s);
                float w  = (stage == 1) ? 1.0f : weight[t];
                float ce = -(w * log_pt);
                float g  = fabsf(expf(log_pt) - 1.0f);
                int b = (int)floorf(g * 9.9999f);   // BINS - EPS_BIN in fp32
                b = b < 0 ? 0 : (b > 9 ? 9 : b);
                if (b == 9) {
                    cnt9++;
                    ce9 += (double)ce;
                } else {
                    atomicAdd(&g_cnt[b], 1u);
                    atomicAdd(&g_ce[b], (double)ce);
                }
            }
        }
    }

    // wave-reduce the dominant bin, one atomic per wave
    #pragma unroll
    for (int off = 32; off > 0; off >>= 1) {
        cnt9 += __shfl_xor(cnt9, off, 64);
        ce9  += __shfl_xor(ce9, off, 64);
    }
    if (lane == 0 && cnt9 > 0) {
        atomicAdd(&g_cnt[9], cnt9);
        atomicAdd(&g_ce[9], ce9);
    }
}

__global__ void ghmc_final_kernel(const double* __restrict__ g_ce,
                                  const unsigned int* __restrict__ g_cnt,
                                  float* __restrict__ out, int N)
{
    if (threadIdx.x == 0) {
        int nonempty = 0;
        #pragma unroll
        for (int b = 0; b < BINS; b++) nonempty += (g_cnt[b] > 0) ? 1 : 0;
        double total = 0.0;
        #pragma unroll
        for (int b = 0; b < BINS; b++) {
            float gd = (float)g_cnt[b] * (float)nonempty;
            gd = fmaxf(gd, 1e-4f);
            total += g_ce[b] / (double)gd;
        }
        out[0] = (float)(total / (double)N);
    }
}

extern "C" void kernel_launch(void* const* d_in, const int* in_sizes, int n_in,
                              void* d_out, int out_size, void* d_ws, size_t ws_size,
                              hipStream_t stream) {
    const float* x       = (const float*)d_in[0];
    const int* target    = (const int*)d_in[1];
    const float* weight  = (const float*)d_in[2];
    const int* stage_p   = (const int*)d_in[3];
    const int N = in_sizes[1];          // rows; C == 64 assumed

    double* g_ce = (double*)d_ws;
    unsigned int* g_cnt = (unsigned int*)(g_ce + BINS);

    hipMemsetAsync(d_ws, 0, BINS * sizeof(double) + BINS * sizeof(unsigned int), stream);

    const int blocks = 2048;            // 8192 waves, grid-stride over row packs
    ghmc_main_kernel<<<blocks, 256, 0, stream>>>(x, target, weight, stage_p,
                                                 g_ce, g_cnt, N);
    ghmc_final_kernel<<<1, 64, 0, stream>>>(g_ce, g_cnt, (float*)d_out, N);
}

// Round 3
// 438.305 us; speedup vs baseline: 1.5294x; 1.5088x over previous
//
#include <hip/hip_runtime.h>
#include <cmath>

// GHM-C two-stage loss, single data pass.
// loss = (1/N) * sum_b beta_b * sum_ce[b],  beta_b = 1/clip(cnt_b*nonempty, 1e-4)
//
// R3: NO global atomics. R1/R2 were serialized by ~36k same-address global
// fp64/u32 atomics (~450 us at ~30 cyc each) — duration was invariant to
// halving VALU work. Now: bin 9 in registers -> wave shfl reduce -> LDS;
// rare bins via LDS atomics (~10 events/block); each block writes its 10-bin
// partial non-atomically to workspace; tiny second kernel reduces partials.

#define BINS 10
#define MAIN_BLOCKS 1024

__global__ __launch_bounds__(256) void ghmc_main_kernel(
    const float* __restrict__ x,
    const int* __restrict__ target,
    const float* __restrict__ weight,
    const int* __restrict__ stage_p,
    double* __restrict__ part_ce,        // [MAIN_BLOCKS * BINS]
    unsigned int* __restrict__ part_cnt, // [MAIN_BLOCKS * BINS]
    int N)
{
    __shared__ double       s_ce[BINS];
    __shared__ unsigned int s_cnt[BINS];
    __shared__ double       s_ce9[4];
    __shared__ unsigned int s_cnt9[4];

    if (threadIdx.x < BINS) { s_ce[threadIdx.x] = 0.0; s_cnt[threadIdx.x] = 0u; }
    __syncthreads();

    const int lane = threadIdx.x & 63;
    const int grp  = lane >> 4;        // row within 4-row pack
    const int sub  = lane & 15;        // float4 index within row
    const int wave_in_block = threadIdx.x >> 6;

    const unsigned int wave_id = blockIdx.x * 4u + (unsigned)wave_in_block;
    const unsigned int nwaves  = MAIN_BLOCKS * 4u;
    const int stage = *stage_p;

    const float4* __restrict__ x4 = (const float4*)x;
    const unsigned int G = ((unsigned int)N + 3u) >> 2;   // 4-row packs

    unsigned int cnt9 = 0;
    double ce9 = 0.0;

    for (unsigned int p = wave_id * 2u; p < G; p += nwaves * 2u) {
        #pragma unroll
        for (int u = 0; u < 2; u++) {
            unsigned int pk = p + (unsigned int)u;
            if (pk >= G) break;
            unsigned int row = pk * 4u + (unsigned int)grp;
            if (row >= (unsigned int)N) continue;

            // lane loads its 4 elements of its row: contiguous 1KiB per wave
            float4 v = x4[((size_t)row << 4) + (unsigned)sub];

            // row max: 3 in-lane + 4 shfl over the 16-lane group
            float m = fmaxf(fmaxf(v.x, v.y), fmaxf(v.z, v.w));
            #pragma unroll
            for (int off = 1; off < 16; off <<= 1)
                m = fmaxf(m, __shfl_xor(m, off, 64));

            // sum of exp(v - m)
            float e0 = expf(v.x - m), e1 = expf(v.y - m);
            float e2 = expf(v.z - m), e3 = expf(v.w - m);
            float s = (e0 + e1) + (e2 + e3);
            #pragma unroll
            for (int off = 1; off < 16; off <<= 1)
                s += __shfl_xor(s, off, 64);

            int t = target[row];   // same addr across the 16-lane group
            if (sub == (t >> 2)) {
                int sl = t & 3;
                float vt = (sl == 0) ? v.x : (sl == 1) ? v.y : (sl == 2) ? v.z : v.w;
                // fp32 sequence mirrors the reference
                float log_pt = (vt - m) - logf(s);
                float w  = (stage == 1) ? 1.0f : weight[t];
                float ce = -(w * log_pt);
                float g  = fabsf(expf(log_pt) - 1.0f);
                int b = (int)floorf(g * 9.9999f);   // BINS - EPS_BIN in fp32
                b = b < 0 ? 0 : (b > 9 ? 9 : b);
                if (b == 9) {
                    cnt9++;
                    ce9 += (double)ce;
                } else {
                    atomicAdd(&s_cnt[b], 1u);       // LDS atomic, rare (~10/block)
                    atomicAdd(&s_ce[b], (double)ce);
                }
            }
        }
    }

    // wave-reduce the dominant bin -> one LDS slot per wave (no atomics)
    #pragma unroll
    for (int off = 32; off > 0; off >>= 1) {
        cnt9 += __shfl_xor(cnt9, off, 64);
        ce9  += __shfl_xor(ce9, off, 64);
    }
    if (lane == 0) { s_ce9[wave_in_block] = ce9; s_cnt9[wave_in_block] = cnt9; }
    __syncthreads();

    if (threadIdx.x == 0) {
        s_ce[9]  += (s_ce9[0] + s_ce9[1]) + (s_ce9[2] + s_ce9[3]);
        s_cnt[9] += s_cnt9[0] + s_cnt9[1] + s_cnt9[2] + s_cnt9[3];
    }
    __syncthreads();

    // non-atomic per-block partial write (every slot overwritten -> no memset)
    if (threadIdx.x < BINS) {
        part_ce [blockIdx.x * BINS + threadIdx.x] = s_ce[threadIdx.x];
        part_cnt[blockIdx.x * BINS + threadIdx.x] = s_cnt[threadIdx.x];
    }
}

__global__ __launch_bounds__(256) void ghmc_final_kernel(
    const double* __restrict__ part_ce,
    const unsigned int* __restrict__ part_cnt,
    float* __restrict__ out, int N)
{
    __shared__ double       s_ce[BINS];
    __shared__ unsigned int s_cnt[BINS];
    if (threadIdx.x < BINS) { s_ce[threadIdx.x] = 0.0; s_cnt[threadIdx.x] = 0u; }
    __syncthreads();

    double       my_ce[BINS];
    unsigned int my_cnt[BINS];
    #pragma unroll
    for (int b = 0; b < BINS; b++) { my_ce[b] = 0.0; my_cnt[b] = 0u; }

    for (int i = threadIdx.x; i < MAIN_BLOCKS; i += 256) {
        #pragma unroll
        for (int b = 0; b < BINS; b++) {
            my_ce[b]  += part_ce [i * BINS + b];
            my_cnt[b] += part_cnt[i * BINS + b];
        }
    }
    #pragma unroll
    for (int b = 0; b < BINS; b++) {
        atomicAdd(&s_ce[b], my_ce[b]);     // LDS atomics, 10 addrs x 256 threads
        atomicAdd(&s_cnt[b], my_cnt[b]);
    }
    __syncthreads();

    if (threadIdx.x == 0) {
        int nonempty = 0;
        #pragma unroll
        for (int b = 0; b < BINS; b++) nonempty += (s_cnt[b] > 0u) ? 1 : 0;
        double total = 0.0;
        #pragma unroll
        for (int b = 0; b < BINS; b++) {
            float gd = (float)s_cnt[b] * (float)nonempty;  // exact ints < 2^24
            gd = fmaxf(gd, 1e-4f);
            total += s_ce[b] / (double)gd;
        }
        out[0] = (float)(total / (double)N);
    }
}

extern "C" void kernel_launch(void* const* d_in, const int* in_sizes, int n_in,
                              void* d_out, int out_size, void* d_ws, size_t ws_size,
                              hipStream_t stream) {
    const float* x       = (const float*)d_in[0];
    const int* target    = (const int*)d_in[1];
    const float* weight  = (const float*)d_in[2];
    const int* stage_p   = (const int*)d_in[3];
    const int N = in_sizes[1];          // rows; C == 64 assumed

    double* part_ce = (double*)d_ws;                      // 1024*10*8 = 80 KiB
    unsigned int* part_cnt = (unsigned int*)(part_ce + MAIN_BLOCKS * BINS);

    ghmc_main_kernel<<<MAIN_BLOCKS, 256, 0, stream>>>(x, target, weight, stage_p,
                                                      part_ce, part_cnt, N);
    ghmc_final_kernel<<<1, 256, 0, stream>>>(part_ce, part_cnt, (float*)d_out, N);
}

// Round 4
// 377.143 us; speedup vs baseline: 1.7774x; 1.1622x over previous
//
#include <hip/hip_runtime.h>
#include <cmath>

// GHM-C two-stage loss, single data pass.
// loss = (1/N) * sum_b beta_b * sum_ce[b],  beta_b = 1/clip(cnt_b*nonempty, 1e-4)
//
// R4: thread-per-row. R3 was latency-bound on the per-row 8-deep cross-lane
// shuffle chain (ds pipe ~60cyc each, only 4 waves/SIMD to hide it). Now:
// single-wave blocks stage 64 rows (16KB) into LDS with coalesced float4
// loads, each thread reduces its OWN row from LDS (32 conflict-free
// ds_read_b64, stride 66 -> 2 lanes/bank = free) with fully-unrolled
// in-register trees. Zero shuffles in the hot loop, no barriers
// (single-wave block = program-ordered LDS).

#define BINS 10
#define MAIN_BLOCKS 2048
#define STRIDE 66            // floats per LDS row; (t*66+2e)/2 %32 = (t+e)%32

__global__ __launch_bounds__(64) void ghmc_main_kernel(
    const float* __restrict__ x,
    const int* __restrict__ target,
    const float* __restrict__ weight,
    const int* __restrict__ stage_p,
    double* __restrict__ part_ce,        // [BINS * MAIN_BLOCKS], bin-major
    unsigned int* __restrict__ part_cnt, // [BINS * MAIN_BLOCKS]
    int N)
{
    __shared__ float        s_x[64 * STRIDE];   // 16896 B
    __shared__ double       s_ce[BINS];
    __shared__ unsigned int s_cnt[BINS];

    const int tid = threadIdx.x;   // 0..63, ONE wave per block
    if (tid < BINS) { s_ce[tid] = 0.0; s_cnt[tid] = 0u; }

    const int stage = *stage_p;
    const float4* __restrict__ x4 = (const float4*)x;
    const unsigned int ntiles = (unsigned int)N >> 6;   // N % 64 == 0

    unsigned int cnt9 = 0;
    double ce9 = 0.0;

    for (unsigned int tile = blockIdx.x; tile < ntiles; tile += MAIN_BLOCKS) {
        const size_t tb4 = (size_t)tile << 10;   // tile*64 rows * 16 float4

        // stage 64 rows, perfectly coalesced (1 KiB per instruction)
        #pragma unroll
        for (int j = 0; j < 16; j++) {
            int i = (j << 6) + tid;              // 0..1023
            float4 vv = x4[tb4 + (unsigned)i];
            int r = i >> 4, c = (i & 15) << 2;
            float* p = &s_x[r * STRIDE + c];
            ((float2*)p)[0]       = make_float2(vv.x, vv.y);
            ((float2*)(p + 2))[0] = make_float2(vv.z, vv.w);
        }

        // thread tid owns row tile*64+tid; 32 independent conflict-free loads
        const float2* __restrict__ vp = (const float2*)&s_x[tid * STRIDE];
        float2 v2[32];
        #pragma unroll
        for (int e = 0; e < 32; e++) v2[e] = vp[e];

        float mx[32];
        #pragma unroll
        for (int e = 0; e < 32; e++) mx[e] = fmaxf(v2[e].x, v2[e].y);
        #pragma unroll
        for (int w = 16; w > 0; w >>= 1) {
            #pragma unroll
            for (int e = 0; e < w; e++) mx[e] = fmaxf(mx[e], mx[e + w]);
        }
        const float m = mx[0];

        float sm[32];
        #pragma unroll
        for (int e = 0; e < 32; e++)
            sm[e] = expf(v2[e].x - m) + expf(v2[e].y - m);
        #pragma unroll
        for (int w = 16; w > 0; w >>= 1) {
            #pragma unroll
            for (int e = 0; e < w; e++) sm[e] += sm[e + w];
        }
        const float s = sm[0];

        int   t  = target[(size_t)tile * 64 + (unsigned)tid];  // coalesced
        float vt = s_x[tid * STRIDE + t];
        // fp32 sequence mirrors the reference
        float log_pt = (vt - m) - logf(s);
        float w  = (stage == 1) ? 1.0f : weight[t];
        float ce = -(w * log_pt);
        float g  = fabsf(expf(log_pt) - 1.0f);
        int b = (int)floorf(g * 9.9999f);     // BINS - EPS_BIN in fp32
        b = b < 0 ? 0 : (b > 9 ? 9 : b);
        if (b == 9) {
            cnt9++;
            ce9 += (double)ce;
        } else {
            atomicAdd(&s_cnt[b], 1u);         // LDS atomic, rare (~1%)
            atomicAdd(&s_ce[b], (double)ce);
        }
    }

    // once per block: wave-reduce the dominant bin
    #pragma unroll
    for (int off = 32; off > 0; off >>= 1) {
        cnt9 += __shfl_xor(cnt9, off, 64);
        ce9  += __shfl_xor(ce9, off, 64);
    }
    if (tid == 0) { s_cnt[9] += cnt9; s_ce[9] += ce9; }

    // single-wave block: program order guarantees LDS visibility
    if (tid < BINS) {
        part_ce [tid * MAIN_BLOCKS + blockIdx.x] = s_ce[tid];
        part_cnt[tid * MAIN_BLOCKS + blockIdx.x] = s_cnt[tid];
    }
}

__global__ __launch_bounds__(1024) void ghmc_final_kernel(
    const double* __restrict__ part_ce,
    const unsigned int* __restrict__ part_cnt,
    float* __restrict__ out, int N)
{
    __shared__ double       s_ce[BINS];
    __shared__ unsigned int s_cnt[BINS];
    if (threadIdx.x < BINS) { s_ce[threadIdx.x] = 0.0; s_cnt[threadIdx.x] = 0u; }
    __syncthreads();

    #pragma unroll
    for (int b = 0; b < BINS; b++) {
        double ce = 0.0; unsigned int cnt = 0u;
        for (int k = threadIdx.x; k < MAIN_BLOCKS; k += 1024) {  // coalesced
            ce  += part_ce [b * MAIN_BLOCKS + k];
            cnt += part_cnt[b * MAIN_BLOCKS + k];
        }
        #pragma unroll
        for (int off = 32; off > 0; off >>= 1) {
            ce  += __shfl_xor(ce, off, 64);
            cnt += __shfl_xor(cnt, off, 64);
        }
        if ((threadIdx.x & 63) == 0) {
            atomicAdd(&s_ce[b], ce);
            atomicAdd(&s_cnt[b], cnt);
        }
    }
    __syncthreads();

    if (threadIdx.x == 0) {
        int nonempty = 0;
        #pragma unroll
        for (int b = 0; b < BINS; b++) nonempty += (s_cnt[b] > 0u) ? 1 : 0;
        double total = 0.0;
        #pragma unroll
        for (int b = 0; b < BINS; b++) {
            float gd = (float)s_cnt[b] * (float)nonempty;  // exact ints < 2^24
            gd = fmaxf(gd, 1e-4f);
            total += s_ce[b] / (double)gd;
        }
        out[0] = (float)(total / (double)N);
    }
}

extern "C" void kernel_launch(void* const* d_in, const int* in_sizes, int n_in,
                              void* d_out, int out_size, void* d_ws, size_t ws_size,
                              hipStream_t stream) {
    const float* x       = (const float*)d_in[0];
    const int* target    = (const int*)d_in[1];
    const float* weight  = (const float*)d_in[2];
    const int* stage_p   = (const int*)d_in[3];
    const int N = in_sizes[1];          // rows; C == 64, N % 64 == 0 assumed

    double* part_ce = (double*)d_ws;                       // 160 KiB
    unsigned int* part_cnt = (unsigned int*)(part_ce + BINS * MAIN_BLOCKS);

    // every partial slot is overwritten by the main kernel -> no memset needed
    ghmc_main_kernel<<<MAIN_BLOCKS, 64, 0, stream>>>(x, target, weight, stage_p,
                                                     part_ce, part_cnt, N);
    ghmc_final_kernel<<<1, 1024, 0, stream>>>(part_ce, part_cnt, (float*)d_out, N);
}